// Round 8
// baseline (55.247 us; speedup 1.0000x reference)
//
#include <hip/hip_runtime.h>
#include <math.h>

// Problem constants (from reference setup_inputs)
#define CDIM 64
#define CR 16
#define TFR 8
#define NBATCH 16      // NT / T
#define NTOT 128       // NT
#define HWPIX 3136     // 56*56
#define HW4 784        // HWPIX / 4

// clang-native 4-float vector: accepted by __builtin_nontemporal_store
typedef float floatx4 __attribute__((ext_vector_type(4)));

// ---------------------------------------------------------------------------
// Kernel 1 (R1-proven): per-(nt, c) spatial mean of x. grid = NT*C = 8192
// blocks x 256 threads; block b reduces x[b*3136 .. +3136).
// Regular loads so x lands in the LLC for kernel 3's re-read.
// ---------------------------------------------------------------------------
__global__ __launch_bounds__(256) void spatial_mean_kernel(
    const float* __restrict__ x, float* __restrict__ xbar) {
  const int b = blockIdx.x;
  const float4* xp = reinterpret_cast<const float4*>(x + (size_t)b * HWPIX);
  float s = 0.f;
  for (int i = threadIdx.x; i < HW4; i += 256) {
    float4 v = xp[i];
    s += (v.x + v.y) + (v.z + v.w);
  }
  #pragma unroll
  for (int off = 32; off > 0; off >>= 1) s += __shfl_down(s, off, 64);
  __shared__ float wsum[4];
  const int lane = threadIdx.x & 63, wid = threadIdx.x >> 6;
  if (lane == 0) wsum[wid] = s;
  __syncthreads();
  if (threadIdx.x == 0) {
    float tot = (wsum[0] + wsum[1]) + (wsum[2] + wsum[3]);
    xbar[b] = tot * (1.0f / (float)HWPIX);
  }
}

// ---------------------------------------------------------------------------
// Kernel 2 (R1-proven, tiny): attp1 per (nt, c). grid = NT blocks x C threads.
// gap[k] = sum_c sq_w[k,c]*(xbar[n,0,c]-xbar[n,t,c])  (0 for t=T-1; sq_b cancels)
// attp1  = 1 + sigmoid(ex_w @ gap + ex_b)
// ---------------------------------------------------------------------------
__global__ __launch_bounds__(64) void att_kernel(
    const float* __restrict__ xbar,
    const float* __restrict__ sq_w,   // (CR, C) row-major
    const float* __restrict__ ex_w,   // (C, CR) row-major
    const float* __restrict__ ex_b,   // (C,)
    float* __restrict__ attp1) {
  const int nt = blockIdx.x;
  const int n = nt >> 3;
  const int t = nt & 7;
  const int c = threadIdx.x;
  __shared__ float d[CDIM];
  __shared__ float gap[CR];
  d[c] = (t == TFR - 1) ? 0.f
                        : (xbar[(n * TFR) * CDIM + c] - xbar[nt * CDIM + c]);
  __syncthreads();
  if (c < CR) {
    float g = 0.f;
    #pragma unroll
    for (int cc = 0; cc < CDIM; ++cc) g += sq_w[c * CDIM + cc] * d[cc];
    gap[c] = g;
  }
  __syncthreads();
  float a = ex_b[c];
  #pragma unroll
  for (int k = 0; k < CR; ++k) a += ex_w[c * CR + k] * gap[k];
  attp1[nt * CDIM + c] = 1.f + 1.f / (1.f + __expf(-a));
}

// ---------------------------------------------------------------------------
// Kernel 3: R1's proven shape (3136 blocks, one float4 column of 8 frames per
// thread), att folded into shift weights. SINGLE CHANGE vs R6: output stores
// are non-temporal so `out` doesn't evict x from the 256 MB LLC — kernel 1
// has just warmed the LLC with all of x (103 MB), and this kernel's re-read
// should then hit LLC instead of HBM.
//   Sc[t] = sb + sw0*ap[t-1]*x[t-1] + sw1*ap[t]*x[t] + sw2*ap[t+1]*x[t+1]
//   Gc[t] = BN(gate-conv_T(x))   [BN folded into conv weights]
//   out   = Sc * sigmoid(Gc)
// ---------------------------------------------------------------------------
__global__ __launch_bounds__(256) void fused_shift_kernel(
    const float* __restrict__ x,
    const float* __restrict__ attp1,
    const float* __restrict__ shift_w, const float* __restrict__ shift_b,
    const float* __restrict__ gate_w,  const float* __restrict__ gate_b,
    const float* __restrict__ bn_gamma, const float* __restrict__ bn_beta,
    const float* __restrict__ bn_mean,  const float* __restrict__ bn_var,
    float* __restrict__ out) {
  const int tid = blockIdx.x * 256 + threadIdx.x;  // 0 .. 16*64*784-1
  const int q = tid % HW4;
  const int c = (tid / HW4) & (CDIM - 1);
  const int n = tid / (HW4 * CDIM);

  const float sw0 = shift_w[c * 3 + 0], sw1 = shift_w[c * 3 + 1],
              sw2 = shift_w[c * 3 + 2], sb = shift_b[c];
  const float inv = bn_gamma[c] * rsqrtf(bn_var[c] + 1e-3f);
  const float g0 = gate_w[c * 3 + 0] * inv, g1 = gate_w[c * 3 + 1] * inv,
              g2 = gate_w[c * 3 + 2] * inv;
  const float gbias = (gate_b[c] - bn_mean[c]) * inv + bn_beta[c];

  // ap[t+1] = attp1(n, t, c); zero-padded ends
  float ap[TFR + 2];
  ap[0] = 0.f;
  ap[TFR + 1] = 0.f;
  #pragma unroll
  for (int t = 0; t < TFR; ++t) ap[t + 1] = attp1[(n * TFR + t) * CDIM + c];

  const size_t base = ((size_t)(n * TFR) * CDIM + c) * HWPIX + (size_t)q * 4;
  const size_t tstride = (size_t)CDIM * HWPIX;  // frame stride in floats

  float4 xv[TFR];
  #pragma unroll
  for (int t = 0; t < TFR; ++t)
    xv[t] = *reinterpret_cast<const float4*>(x + base + (size_t)t * tstride);

  const float4 zero4 = make_float4(0.f, 0.f, 0.f, 0.f);
  #pragma unroll
  for (int t = 0; t < TFR; ++t) {
    const float e0 = sw0 * ap[t], e1 = sw1 * ap[t + 1], e2 = sw2 * ap[t + 2];
    const float4 xm = (t > 0) ? xv[t - 1] : zero4;
    const float4 xp = (t < TFR - 1) ? xv[t + 1] : zero4;
    floatx4 o;
    {
      const float sc = sb + e0 * xm.x + e1 * xv[t].x + e2 * xp.x;
      const float gc = gbias + g0 * xm.x + g1 * xv[t].x + g2 * xp.x;
      o.x = sc * (1.f / (1.f + __expf(-gc)));
    }
    {
      const float sc = sb + e0 * xm.y + e1 * xv[t].y + e2 * xp.y;
      const float gc = gbias + g0 * xm.y + g1 * xv[t].y + g2 * xp.y;
      o.y = sc * (1.f / (1.f + __expf(-gc)));
    }
    {
      const float sc = sb + e0 * xm.z + e1 * xv[t].z + e2 * xp.z;
      const float gc = gbias + g0 * xm.z + g1 * xv[t].z + g2 * xp.z;
      o.z = sc * (1.f / (1.f + __expf(-gc)));
    }
    {
      const float sc = sb + e0 * xm.w + e1 * xv[t].w + e2 * xp.w;
      const float gc = gbias + g0 * xm.w + g1 * xv[t].w + g2 * xp.w;
      o.w = sc * (1.f / (1.f + __expf(-gc)));
    }
    __builtin_nontemporal_store(
        o, reinterpret_cast<floatx4*>(out + base + (size_t)t * tstride));
  }
}

extern "C" void kernel_launch(void* const* d_in, const int* in_sizes, int n_in,
                              void* d_out, int out_size, void* d_ws, size_t ws_size,
                              hipStream_t stream) {
  const float* x        = (const float*)d_in[0];
  const float* shift_w  = (const float*)d_in[1];
  const float* shift_b  = (const float*)d_in[2];
  const float* gate_w   = (const float*)d_in[3];
  const float* gate_b   = (const float*)d_in[4];
  const float* bn_gamma = (const float*)d_in[5];
  const float* bn_beta  = (const float*)d_in[6];
  const float* bn_mean  = (const float*)d_in[7];
  const float* bn_var   = (const float*)d_in[8];
  const float* sq_w     = (const float*)d_in[9];
  // d_in[10] = sq_b  (cancels in temporal diff -> unused)
  const float* ex_w     = (const float*)d_in[11];
  const float* ex_b     = (const float*)d_in[12];
  float* out = (float*)d_out;

  float* xbar  = (float*)d_ws;                 // NT*C floats
  float* attp1 = (float*)d_ws + NTOT * CDIM;   // NT*C floats

  spatial_mean_kernel<<<NTOT * CDIM, 256, 0, stream>>>(x, xbar);
  att_kernel<<<NTOT, CDIM, 0, stream>>>(xbar, sq_w, ex_w, ex_b, attp1);
  fused_shift_kernel<<<(NBATCH * CDIM * HW4) / 256, 256, 0, stream>>>(
      x, attp1, shift_w, shift_b, gate_w, gate_b,
      bn_gamma, bn_beta, bn_mean, bn_var, out);
}